// Round 2
// baseline (3539.116 us; speedup 1.0000x reference)
//
#include <hip/hip_runtime.h>

typedef unsigned int uint;

#define N_NODES 1000000
#define D       128
#define T_STEPS 100
#define B       1024
#define K       6
#define ALPHA   0.025f

#define NBLK  256
#define TPB   256
#define NWAVE 1024                 // NBLK*TPB/64 == B (one wave per edge)
#define NGRP  16
#define GRPSZ 16                   // NBLK / NGRP

// ws layout (uint granularity):
//   root[k]   at ROOT_OFF + k*16          (64B stride, 256 slots -> 16 KB)
//   grp[k][g] at GRP_OFF + (k*NGRP+g)*16  (64B stride -> 256 KB)
//   flags[r]  at FLAG_OFF                  (N_NODES uints = 4 MB, SPARSE only)
#define ROOT_OFF  0
#define GRP_OFF   4096
#define FLAG_OFF  69632
#define CNT_BYTES ((size_t)FLAG_OFF * 4)                       // 278528 B (< 512 KB proven)
#define SPARSE_BYTES ((size_t)(FLAG_OFF + N_NODES) * 4)        // ~4.3 MB

__device__ __forceinline__ float wave_sum(float v) {
#pragma unroll
    for (int off = 32; off; off >>= 1) v += __shfl_xor(v, off, 64);
    return v;
}

// 8-byte agent-scope (device) atomic load: always observes LLC-coherent data,
// immune to any stale per-XCD L2 line. Used for rows mutated by scatters.
__device__ __forceinline__ float2 aload8(const float* p) {
    unsigned long long v = __hip_atomic_load((const unsigned long long*)p,
                                             __ATOMIC_RELAXED,
                                             __HIP_MEMORY_SCOPE_AGENT);
    union { unsigned long long u; float2 f; } c; c.u = v;
    return c.f;
}

// Two-level software grid barrier. Each rendezvous k uses its own zeroed slot
// (hipMemsetAsync before the kernel), so no sense-reversal and replays are clean.
// thread0: release fence -> group counter -> root counter -> spin root==NGRP ->
// acquire fence. __syncthreads drains each thread's own vmem (vmcnt(0)) before
// arrival and publishes the fence's cache-invalidate to the block after release.
__device__ __forceinline__ void grid_barrier(uint* ws_u, int k) {
    __syncthreads();
    if (threadIdx.x == 0) {
        __threadfence();                                   // release (wb L2)
        const uint g = (uint)blockIdx.x & (NGRP - 1);
        uint* grpc = &ws_u[GRP_OFF + (k * NGRP + (int)g) * 16];
        if (atomicAdd(grpc, 1u) == GRPSZ - 1)
            atomicAdd(&ws_u[ROOT_OFF + k * 16], 1u);
        while (__hip_atomic_load(&ws_u[ROOT_OFF + k * 16], __ATOMIC_RELAXED,
                                 __HIP_MEMORY_SCOPE_AGENT) != NGRP)
            __builtin_amdgcn_s_sleep(2);
        __threadfence();                                   // acquire (inv L1/L2)
    }
    __syncthreads();
}

template <bool SPARSE>
__global__ __launch_bounds__(TPB) void line_fused(const float* __restrict__ emb_in,
                                                  const int*   __restrict__ u_idx,   // [T*B]
                                                  const int*   __restrict__ tgt_idx, // [T*B*K]
                                                  float*       __restrict__ out,
                                                  uint*        ws_u)
{
    const int tid  = blockIdx.x * TPB + threadIdx.x;
    const int wave = tid >> 6;                // 0..1023  == edge id b
    const int lane = threadIdx.x & 63;
    uint* flags = ws_u + FLAG_OFF;
    int bar = 0;

    // ---------------- prologue: materialize mutable rows in `out` ----------------
    if (SPARSE) {
        // Every row that is EVER updated is a u_idx entry (known statically).
        // Duplicate copies write identical bytes -> benign.
#pragma unroll 2
        for (int e = wave; e < T_STEPS * B; e += NWAVE) {
            const int r = u_idx[e];
            if (lane == 0) flags[r] = 1u;
            const size_t off = (size_t)r * D + 2 * lane;
            *(float2*)(out + off) = *(const float2*)(emb_in + off);
        }
    } else {
        const float4* src = (const float4*)emb_in;
        float4*       dst = (float4*)out;
#pragma unroll 4
        for (int i = tid; i < N_NODES * D / 4; i += NBLK * TPB) dst[i] = src[i];
    }
    grid_barrier(ws_u, bar++);

    // ---------------- 100 sequential SGD steps ----------------
    const int b = wave;
    int  cu, cv[K];
    uint fv[K];
    {   // step-0 indices + flags (flags valid only after prologue barrier)
        cu = u_idx[b];
#pragma unroll
        for (int k = 0; k < K; ++k) cv[k] = tgt_idx[b * K + k];
#pragma unroll
        for (int k = 0; k < K; ++k) fv[k] = SPARSE ? flags[cv[k]] : 1u;
    }
    float2 v2[K];
    // step-0 immutable gathers (emb_in never changes -> no ordering needed)
#pragma unroll
    for (int k = 0; k < K; ++k)
        if (!fv[k]) v2[k] = *(const float2*)(emb_in + (size_t)cv[k] * D + 2 * lane);

    for (int t = 0; t < T_STEPS; ++t) {
        // mutable-row gathers: state after step t-1's scatter barrier
        float2 u2 = aload8(out + (size_t)cu * D + 2 * lane);
#pragma unroll
        for (int k = 0; k < K; ++k)
            if (fv[k]) v2[k] = aload8(out + (size_t)cv[k] * D + 2 * lane);

        // prefetch next step's indices + flags (static data, overlaps compute)
        int  ncu = 0, ncv[K];
        uint nfv[K];
        if (t + 1 < T_STEPS) {
            const int nb = (t + 1) * B + b;
            ncu = u_idx[nb];
#pragma unroll
            for (int k = 0; k < K; ++k) ncv[k] = tgt_idx[nb * K + k];
#pragma unroll
            for (int k = 0; k < K; ++k) nfv[k] = SPARSE ? flags[ncv[k]] : 1u;
        } else {
#pragma unroll
            for (int k = 0; k < K; ++k) { ncv[k] = 0; nfv[k] = 1u; }
        }

        // compute err = sum_k g_k * v_k  (v_k are pre-step values)
        float2 e2 = make_float2(0.f, 0.f);
#pragma unroll
        for (int k = 0; k < K; ++k) {
            const float s = wave_sum(u2.x * v2[k].x + u2.y * v2[k].y);
            const float f = 1.f / (1.f + expf(-s));
            const float g = ALPHA * ((k == 0 ? 1.f : 0.f) - f);
            e2.x += g * v2[k].x;
            e2.y += g * v2[k].y;
        }

        grid_barrier(ws_u, bar++);           // A: all gathers of step t done

        float* urow = out + (size_t)cu * D + 2 * lane;
        atomicAdd(urow,     e2.x);
        atomicAdd(urow + 1, e2.y);

        // overlap: next step's immutable gathers while scatters drain
        if (t + 1 < T_STEPS) {
#pragma unroll
            for (int k = 0; k < K; ++k)
                if (!nfv[k]) v2[k] = *(const float2*)(emb_in + (size_t)ncv[k] * D + 2 * lane);
        }

        grid_barrier(ws_u, bar++);           // B: all scatters of step t visible

        cu = ncu;
#pragma unroll
        for (int k = 0; k < K; ++k) { cv[k] = ncv[k]; fv[k] = nfv[k]; }
    }

    // ---------------- final L2 row-normalize (reads per-flag, writes all) --------
#define RPI 8
    for (int r0 = wave * RPI; r0 < N_NODES; r0 += NWAVE * RPI) {
        float2 rv[RPI];
#pragma unroll
        for (int j = 0; j < RPI; ++j) {
            const int r = r0 + j;
            if (r < N_NODES) {
                const uint fl = SPARSE ? flags[r] : 1u;
                const size_t off = (size_t)r * D + 2 * lane;
                rv[j] = fl ? *(const float2*)(out + off)
                           : *(const float2*)(emb_in + off);
            }
        }
#pragma unroll
        for (int j = 0; j < RPI; ++j) {
            const int r = r0 + j;
            if (r < N_NODES) {
                const float ss  = wave_sum(rv[j].x * rv[j].x + rv[j].y * rv[j].y);
                const float inv = 1.f / fmaxf(sqrtf(ss), 1e-12f);
                const size_t off = (size_t)r * D + 2 * lane;
                *(float2*)(out + off) = make_float2(rv[j].x * inv, rv[j].y * inv);
            }
        }
    }
}

extern "C" void kernel_launch(void* const* d_in, const int* in_sizes, int n_in,
                              void* d_out, int out_size, void* d_ws, size_t ws_size,
                              hipStream_t stream)
{
    const float* emb_in  = (const float*)d_in[0];
    const int*   u_idx   = (const int*)d_in[1];
    const int*   tgt_idx = (const int*)d_in[2];
    float*       out     = (float*)d_out;
    uint*        ws_u    = (uint*)d_ws;

    const bool sparse = ws_size >= SPARSE_BYTES;
    // zero barrier slots (+ flags in sparse mode) -> deterministic every replay
    hipMemsetAsync(d_ws, 0, sparse ? SPARSE_BYTES : CNT_BYTES, stream);

    if (sparse)
        line_fused<true><<<NBLK, TPB, 0, stream>>>(emb_in, u_idx, tgt_idx, out, ws_u);
    else
        line_fused<false><<<NBLK, TPB, 0, stream>>>(emb_in, u_idx, tgt_idx, out, ws_u);
}

// Round 3
// 1094.417 us; speedup vs baseline: 3.2338x; 3.2338x over previous
//
#include <hip/hip_runtime.h>

typedef unsigned int uint;

#define N_NODES 1000000
#define D       128
#define T_STEPS 100
#define B       1024
#define K       6
#define ALPHA   0.025f

// persistent loop kernel geometry: exactly B waves
#define LNBLK  128
#define LTPB   512
#define NGRP   16
#define GRPSZ  8                   // LNBLK / NGRP

// ws layout (uint granularity):
//   root[k]   at ROOT_OFF + k*16          (64B stride, 256 slots)
//   grp[k][g] at GRP_OFF + (k*NGRP+g)*16  (64B stride)
//   flags[r]  at FLAG_OFF                 (N_NODES uints, SPARSE only)
#define ROOT_OFF  0
#define GRP_OFF   4096
#define FLAG_OFF  69632
#define CNT_BYTES    ((size_t)FLAG_OFF * 4)                 // 278528 B (< 512 KB proven)
#define SPARSE_BYTES ((size_t)(FLAG_OFF + N_NODES) * 4)     // ~4.3 MB (proven fits, round 2)

__device__ __forceinline__ float wave_sum(float v) {
#pragma unroll
    for (int off = 32; off; off >>= 1) v += __shfl_xor(v, off, 64);
    return v;
}

// 8-byte agent-scope atomic load: served at the coherent point (LLC), immune to
// stale per-XCD L2 lines. Used for all rows mutated by atomicAdd scatters.
__device__ __forceinline__ float2 aload8(const float* p) {
    unsigned long long v = __hip_atomic_load((const unsigned long long*)p,
                                             __ATOMIC_RELAXED,
                                             __HIP_MEMORY_SCOPE_AGENT);
    union { unsigned long long u; float2 f; } c; c.u = v;
    return c.f;
}

// Fence-FREE two-level grid barrier. Valid because every cross-block datum in
// this kernel moves via device-scope atomics (executed at the LLC): there are
// no dirty L2 lines to publish and no stale L2 lines to invalidate.
// __syncthreads() drains each thread's vmcnt(0) (compiler emits the full
// s_waitcnt before s_barrier), so all scatter atomics are complete at the LLC
// before thread0 signals. Each rendezvous k uses its own pre-zeroed slot.
__device__ __forceinline__ void grid_barrier(uint* ws_u, int k) {
    __syncthreads();
    if (threadIdx.x == 0) {
        asm volatile("" ::: "memory");
        const uint g = (uint)blockIdx.x & (NGRP - 1);
        uint* grpc = &ws_u[GRP_OFF + (k * NGRP + (int)g) * 16];
        if (atomicAdd(grpc, 1u) == GRPSZ - 1u)
            atomicAdd(&ws_u[ROOT_OFF + k * 16], 1u);
        while (__hip_atomic_load(&ws_u[ROOT_OFF + k * 16], __ATOMIC_RELAXED,
                                 __HIP_MEMORY_SCOPE_AGENT) != NGRP)
            __builtin_amdgcn_s_sleep(1);
        asm volatile("" ::: "memory");
    }
    __syncthreads();
}

// ---------------- prologue: flags + materialize mutable rows in `out` -----------
template <bool SPARSE>
__global__ __launch_bounds__(256) void prologue(const float* __restrict__ emb_in,
                                                const int*   __restrict__ u_idx, // [T*B]
                                                float*       __restrict__ out,
                                                uint*        __restrict__ flags)
{
    if (SPARSE) {
        const int wave = (blockIdx.x * 256 + threadIdx.x) >> 6;
        const int lane = threadIdx.x & 63;
        const int nw = gridDim.x * 4;
        for (int e = wave; e < T_STEPS * B; e += nw) {
            const int r = u_idx[e];
            if (lane == 0) flags[r] = 1u;            // dups write identical bytes
            const size_t off = (size_t)r * D + 2 * lane;
            *(float2*)(out + off) = *(const float2*)(emb_in + off);
        }
    } else {
        const int tid = blockIdx.x * 256 + threadIdx.x;
        const int stride = gridDim.x * 256;
        const float4* src = (const float4*)emb_in;
        float4*       dst = (float4*)out;
        for (int i = tid; i < N_NODES * D / 4; i += stride) dst[i] = src[i];
    }
}

// ---------------- persistent SGD loop: 100 steps, 200 fence-free barriers -------
template <bool SPARSE>
__global__ __launch_bounds__(LTPB) void line_loop(const float* __restrict__ emb_in,
                                                  const int*   __restrict__ u_idx,   // [T*B]
                                                  const int*   __restrict__ tgt_idx, // [T*B*K]
                                                  float*       __restrict__ out,
                                                  uint*        ws_u)
{
    const int wave = (blockIdx.x * LTPB + threadIdx.x) >> 6; // 0..1023 == edge b
    const int lane = threadIdx.x & 63;
    const uint* flags = ws_u + FLAG_OFF;   // immutable in this kernel -> plain cached loads
    const int b = wave;
    int bar = 0;

    int  cu, cv[K];
    uint fv[K];
    cu = u_idx[b];
#pragma unroll
    for (int k = 0; k < K; ++k) cv[k] = tgt_idx[b * K + k];
#pragma unroll
    for (int k = 0; k < K; ++k) fv[k] = SPARSE ? flags[cv[k]] : 1u;

    float2 v2[K];
    // step-0 immutable gathers (emb_in never written -> no ordering needed)
#pragma unroll
    for (int k = 0; k < K; ++k)
        if (!fv[k]) v2[k] = *(const float2*)(emb_in + (size_t)cv[k] * D + 2 * lane);

    for (int t = 0; t < T_STEPS; ++t) {
        // mutable-row gathers: LLC-coherent, state after step t-1's barrier B
        float2 u2 = aload8(out + (size_t)cu * D + 2 * lane);
#pragma unroll
        for (int k = 0; k < K; ++k)
            if (fv[k]) v2[k] = aload8(out + (size_t)cv[k] * D + 2 * lane);

        // prefetch next step's indices + flags (static data, overlaps gathers)
        int  ncu = 0, ncv[K];
        uint nfv[K];
        if (t + 1 < T_STEPS) {
            const int nb = (t + 1) * B + b;
            ncu = u_idx[nb];
#pragma unroll
            for (int k = 0; k < K; ++k) ncv[k] = tgt_idx[nb * K + k];
#pragma unroll
            for (int k = 0; k < K; ++k) nfv[k] = SPARSE ? flags[ncv[k]] : 1u;
        } else {
#pragma unroll
            for (int k = 0; k < K; ++k) { ncv[k] = 0; nfv[k] = 1u; }
        }

        // err = sum_k g_k * v_k   (v_k are pre-step values)
        float2 e2 = make_float2(0.f, 0.f);
#pragma unroll
        for (int k = 0; k < K; ++k) {
            const float s = wave_sum(u2.x * v2[k].x + u2.y * v2[k].y);
            const float f = 1.f / (1.f + expf(-s));
            const float g = ALPHA * ((k == 0 ? 1.f : 0.f) - f);
            e2.x += g * v2[k].x;
            e2.y += g * v2[k].y;
        }

        grid_barrier(ws_u, bar++);            // A: all gathers of step t done

        float* urow = out + (size_t)cu * D + 2 * lane;
        atomicAdd(urow,     e2.x);            // RMW at LLC -> coherent
        atomicAdd(urow + 1, e2.y);

        // next step's immutable gathers overlap the scatter drain
        if (t + 1 < T_STEPS) {
#pragma unroll
            for (int k = 0; k < K; ++k)
                if (!nfv[k]) v2[k] = *(const float2*)(emb_in + (size_t)ncv[k] * D + 2 * lane);
        }

        grid_barrier(ws_u, bar++);            // B: all scatters of step t at LLC

        cu = ncu;
#pragma unroll
        for (int k = 0; k < K; ++k) { cv[k] = ncv[k]; fv[k] = nfv[k]; }
    }
}

// ---------------- final L2 row-normalize: full-BW streaming kernel --------------
template <bool SPARSE>
__global__ __launch_bounds__(256) void normalize_k(const float* __restrict__ emb_in,
                                                   float*       __restrict__ out,
                                                   const uint*  __restrict__ flags)
{
    const int wave = (blockIdx.x * 256 + threadIdx.x) >> 6;
    const int lane = threadIdx.x & 63;
    const int nw = gridDim.x * 4;
    for (int r0 = wave * 4; r0 < N_NODES; r0 += nw * 4) {
        uint4 f4 = SPARSE ? *(const uint4*)(flags + r0) : make_uint4(1u, 1u, 1u, 1u);
        const uint fl[4] = { f4.x, f4.y, f4.z, f4.w };
        float2 v[4];
#pragma unroll
        for (int j = 0; j < 4; ++j) {
            const float* src = fl[j] ? out : emb_in;   // wave-uniform branch
            v[j] = *(const float2*)(src + (size_t)(r0 + j) * D + 2 * lane);
        }
#pragma unroll
        for (int j = 0; j < 4; ++j) {
            const float ss  = wave_sum(v[j].x * v[j].x + v[j].y * v[j].y);
            const float inv = 1.f / fmaxf(sqrtf(ss), 1e-12f);
            *(float2*)(out + (size_t)(r0 + j) * D + 2 * lane) =
                make_float2(v[j].x * inv, v[j].y * inv);
        }
    }
}

extern "C" void kernel_launch(void* const* d_in, const int* in_sizes, int n_in,
                              void* d_out, int out_size, void* d_ws, size_t ws_size,
                              hipStream_t stream)
{
    const float* emb_in  = (const float*)d_in[0];
    const int*   u_idx   = (const int*)d_in[1];
    const int*   tgt_idx = (const int*)d_in[2];
    float*       out     = (float*)d_out;
    uint*        ws_u    = (uint*)d_ws;
    uint*        flags   = ws_u + FLAG_OFF;

    const bool sparse = ws_size >= SPARSE_BYTES;   // round-2 counters prove this holds
    hipMemsetAsync(d_ws, 0, sparse ? SPARSE_BYTES : CNT_BYTES, stream);

    if (sparse) {
        prologue<true> <<<1024, 256, 0, stream>>>(emb_in, u_idx, out, flags);
        line_loop<true> <<<LNBLK, LTPB, 0, stream>>>(emb_in, u_idx, tgt_idx, out, ws_u);
        normalize_k<true> <<<2048, 256, 0, stream>>>(emb_in, out, flags);
    } else {
        prologue<false> <<<2048, 256, 0, stream>>>(emb_in, u_idx, out, flags);
        line_loop<false> <<<LNBLK, LTPB, 0, stream>>>(emb_in, u_idx, tgt_idx, out, ws_u);
        normalize_k<false> <<<2048, 256, 0, stream>>>(emb_in, out, flags);
    }
}

// Round 4
// 764.527 us; speedup vs baseline: 4.6292x; 1.4315x over previous
//
#include <hip/hip_runtime.h>

typedef unsigned int uint;

#define N_NODES 1000000
#define D       128
#define T_STEPS 100
#define B       1024
#define K       6
#define ALPHA   0.025f

// persistent loop kernel: 64 blocks x 1024 threads = 1024 waves = B edges
#define LNBLK  64
#define LTPB   1024

// ws layout (uint granularity):
//   root[k]  at k*16 (64B stride), k < 256  -> 16 KB
//   flags[r] at FLAG_OFF (N_NODES uints = 4 MB, SPARSE only)
#define FLAG_OFF     4096
#define CNT_BYTES    ((size_t)FLAG_OFF * 4)              // 16 KB
#define SPARSE_BYTES ((size_t)(FLAG_OFF + N_NODES) * 4)  // ~4.02 MB (fits: round-2/3 proven)

__device__ __forceinline__ float wave_sum(float v) {
#pragma unroll
    for (int off = 32; off; off >>= 1) v += __shfl_xor(v, off, 64);
    return v;
}

// 8-byte agent-scope atomic load: served at the coherent point (LLC), immune to
// stale per-XCD L2 lines. Used for all rows mutated by atomicAdd scatters.
__device__ __forceinline__ float2 aload8(const float* p) {
    unsigned long long v = __hip_atomic_load((const unsigned long long*)p,
                                             __ATOMIC_RELAXED,
                                             __HIP_MEMORY_SCOPE_AGENT);
    union { unsigned long long u; float2 f; } c; c.u = v;
    return c.f;
}

// Split-phase fence-free grid barrier (single level, LNBLK participants).
// Valid because every cross-block datum moves via device-scope atomics at the
// LLC: nothing dirty to publish, nothing stale to invalidate (round-3 verified).
// arrive(): __syncthreads drains each thread's vmcnt(0) (compiler emits the
// full s_waitcnt before s_barrier), so the block's gathers/scatter-atomics are
// complete at the LLC before thread0 signals arrival.
// wait(): spin until all blocks arrived, then block-wide release.
// Work placed between arrive() and wait() hides the rendezvous latency.
__device__ __forceinline__ void bar_arrive(uint* root, int k) {
    __syncthreads();
    if (threadIdx.x == 0) atomicAdd(&root[k * 16], 1u);
}
__device__ __forceinline__ void bar_wait(uint* root, int k) {
    if (threadIdx.x == 0) {
        while (__hip_atomic_load(&root[k * 16], __ATOMIC_RELAXED,
                                 __HIP_MEMORY_SCOPE_AGENT) < (uint)LNBLK)
            __builtin_amdgcn_s_sleep(1);
    }
    __syncthreads();
}

// ---------------- prologue: flags + materialize mutable rows in `out` ----------
template <bool SPARSE>
__global__ __launch_bounds__(256) void prologue(const float* __restrict__ emb_in,
                                                const int*   __restrict__ u_idx, // [T*B]
                                                float*       __restrict__ out,
                                                uint*        __restrict__ flags)
{
    if (SPARSE) {
        const int wave = (blockIdx.x * 256 + threadIdx.x) >> 6;
        const int lane = threadIdx.x & 63;
        const int nw = gridDim.x * 4;
        for (int e = wave; e < T_STEPS * B; e += nw) {
            const int r = u_idx[e];
            if (lane == 0) flags[r] = 1u;            // dups write identical bytes
            const size_t off = (size_t)r * D + 2 * lane;
            *(float2*)(out + off) = *(const float2*)(emb_in + off);
        }
    } else {
        const int tid = blockIdx.x * 256 + threadIdx.x;
        const int stride = gridDim.x * 256;
        const float4* src = (const float4*)emb_in;
        float4*       dst = (float4*)out;
        for (int i = tid; i < N_NODES * D / 4; i += stride) dst[i] = src[i];
    }
}

// ---------------- persistent SGD loop: 100 steps, split-phase barriers ---------
template <bool SPARSE>
__global__ __launch_bounds__(LTPB) void line_loop(const float* __restrict__ emb_in,
                                                  const int*   __restrict__ u_idx,   // [T*B]
                                                  const int*   __restrict__ tgt_idx, // [T*B*K]
                                                  float*       __restrict__ out,
                                                  uint*        ws_u)
{
    const int wave = (blockIdx.x * LTPB + threadIdx.x) >> 6; // 0..1023 == edge b
    const int lane = threadIdx.x & 63;
    const uint* flags = ws_u + FLAG_OFF;  // immutable here -> plain cached loads
    uint* root = ws_u;
    const int b = wave;

    int  cu, cv[K];
    uint fv[K];
    cu = u_idx[b];
#pragma unroll
    for (int k = 0; k < K; ++k) cv[k] = tgt_idx[b * K + k];
#pragma unroll
    for (int k = 0; k < K; ++k) fv[k] = SPARSE ? flags[cv[k]] : 1u;

    float2 v2[K];
    // step-0 immutable gathers (emb_in never written -> any cache OK)
#pragma unroll
    for (int k = 0; k < K; ++k)
        if (!fv[k]) v2[k] = *(const float2*)(emb_in + (size_t)cv[k] * D + 2 * lane);

    for (int t = 0; t < T_STEPS; ++t) {
        // mutable gathers: LLC-coherent, see state after step t-1's barrier B
        float2 u2 = aload8(out + (size_t)cu * D + 2 * lane);
#pragma unroll
        for (int k = 0; k < K; ++k)
            if (fv[k]) v2[k] = aload8(out + (size_t)cv[k] * D + 2 * lane);

        // next-step index/flag loads issue here, overlapping gather latency
        int  ncu = 0, ncv[K];
        uint nfv[K];
        if (t + 1 < T_STEPS) {
            const int nb = (t + 1) * B + b;
            ncu = u_idx[nb];
#pragma unroll
            for (int k = 0; k < K; ++k) ncv[k] = tgt_idx[nb * K + k];
#pragma unroll
            for (int k = 0; k < K; ++k) nfv[k] = SPARSE ? flags[ncv[k]] : 1u;
        } else {
#pragma unroll
            for (int k = 0; k < K; ++k) { ncv[k] = 0; nfv[k] = 1u; }
        }

        bar_arrive(root, 2 * t);           // signals: my gathers are complete

        // err = sum_k g_k * v_k -- pure register work, hides rendezvous A
        float2 e2 = make_float2(0.f, 0.f);
#pragma unroll
        for (int k = 0; k < K; ++k) {
            const float s = wave_sum(u2.x * v2[k].x + u2.y * v2[k].y);
            const float f = 1.f / (1.f + __expf(-s));
            const float g = ALPHA * ((k == 0 ? 1.f : 0.f) - f);
            e2.x += g * v2[k].x;
            e2.y += g * v2[k].y;
        }

        bar_wait(root, 2 * t);             // all gathers of step t done grid-wide

        float* urow = out + (size_t)cu * D + 2 * lane;
        atomicAdd(urow,     e2.x);         // RMW at LLC -> coherent
        atomicAdd(urow + 1, e2.y);

        if (t + 1 < T_STEPS) {
            bar_arrive(root, 2 * t + 1);   // syncthreads drained the scatters
            // next step's immutable gathers hide rendezvous B
#pragma unroll
            for (int k = 0; k < K; ++k)
                if (!nfv[k]) v2[k] = *(const float2*)(emb_in + (size_t)ncv[k] * D + 2 * lane);
            bar_wait(root, 2 * t + 1);     // all scatters of step t at LLC
        }
        // last step: kernel boundary is the barrier before normalize_k

        cu = ncu;
#pragma unroll
        for (int k = 0; k < K; ++k) { cv[k] = ncv[k]; fv[k] = nfv[k]; }
    }
}

// ---------------- final L2 row-normalize: full-BW streaming kernel -------------
template <bool SPARSE>
__global__ __launch_bounds__(256) void normalize_k(const float* __restrict__ emb_in,
                                                   float*       __restrict__ out,
                                                   const uint*  __restrict__ flags)
{
    const int wave = (blockIdx.x * 256 + threadIdx.x) >> 6;
    const int lane = threadIdx.x & 63;
    const int nw = gridDim.x * 4;
    for (int r0 = wave * 4; r0 < N_NODES; r0 += nw * 4) {
        uint4 f4 = SPARSE ? *(const uint4*)(flags + r0) : make_uint4(1u, 1u, 1u, 1u);
        const uint fl[4] = { f4.x, f4.y, f4.z, f4.w };
        float2 v[4];
#pragma unroll
        for (int j = 0; j < 4; ++j) {
            const float* src = fl[j] ? out : emb_in;   // wave-uniform branch
            v[j] = *(const float2*)(src + (size_t)(r0 + j) * D + 2 * lane);
        }
#pragma unroll
        for (int j = 0; j < 4; ++j) {
            const float ss  = wave_sum(v[j].x * v[j].x + v[j].y * v[j].y);
            const float inv = 1.f / fmaxf(sqrtf(ss), 1e-12f);
            *(float2*)(out + (size_t)(r0 + j) * D + 2 * lane) =
                make_float2(v[j].x * inv, v[j].y * inv);
        }
    }
}

extern "C" void kernel_launch(void* const* d_in, const int* in_sizes, int n_in,
                              void* d_out, int out_size, void* d_ws, size_t ws_size,
                              hipStream_t stream)
{
    const float* emb_in  = (const float*)d_in[0];
    const int*   u_idx   = (const int*)d_in[1];
    const int*   tgt_idx = (const int*)d_in[2];
    float*       out     = (float*)d_out;
    uint*        ws_u    = (uint*)d_ws;
    uint*        flags   = ws_u + FLAG_OFF;

    const bool sparse = ws_size >= SPARSE_BYTES;
    hipMemsetAsync(d_ws, 0, sparse ? SPARSE_BYTES : CNT_BYTES, stream);

    if (sparse) {
        prologue<true>  <<<1024, 256, 0, stream>>>(emb_in, u_idx, out, flags);
        line_loop<true> <<<LNBLK, LTPB, 0, stream>>>(emb_in, u_idx, tgt_idx, out, ws_u);
        normalize_k<true> <<<2048, 256, 0, stream>>>(emb_in, out, flags);
    } else {
        prologue<false>  <<<2048, 256, 0, stream>>>(emb_in, u_idx, out, flags);
        line_loop<false> <<<LNBLK, LTPB, 0, stream>>>(emb_in, u_idx, tgt_idx, out, ws_u);
        normalize_k<false> <<<2048, 256, 0, stream>>>(emb_in, out, flags);
    }
}